// Round 1
// baseline (343.419 us; speedup 1.0000x reference)
//
#include <hip/hip_runtime.h>

// Tile geometry
#define TW   128
#define TH   32
#define HALO 5
#define TIW  (TW + 2*HALO)   // 138
#define TIH  (TH + 2*HALO)   // 42
#define TB_P 144             // byte row stride for tb (padding)
#define VS_P 142             // u16 row stride for vs (odd 4B-word stride -> conflict-free halves)
#define NBX  8
#define NBY  32
#define NBZ  16
#define NB   (NBX*NBY*NBZ)   // 4096 blocks
#define NPIX 16777216.0      // 16*1024*1024

// Fused: edge-mask (11x11 Laplacian != 0) + per-pixel label-smoothing loss partials.
// Decomposition: sum_c mask*logp = lp_t + e*alpha*(lp0+lp1 - 1.5*lp_t), alpha global.
// Per block writes 5 partial sums: [cnt_e, S1_score0, S2_score0, S1_score1, S2_score1].
__global__ __launch_bounds__(256)
void fused_edge_loss(const float* __restrict__ score0,
                     const float* __restrict__ score1,
                     const int*   __restrict__ target,
                     float*       __restrict__ ws) {
    __shared__ unsigned char  tb[TIH][TB_P];
    __shared__ unsigned short vs[TH][VS_P];
    __shared__ float          red[4][5];

    const int tid   = threadIdx.x;
    const int tileX = blockIdx.x * TW;
    const int tileY = blockIdx.y * TH;
    const int b     = blockIdx.z;
    const int bid   = (blockIdx.z * NBY + blockIdx.y) * NBX + blockIdx.x;

    const int* tgt = target + (size_t)b * (1024 * 1024);

    // ---- Phase A: stage target tile + halo into LDS (zeros outside image) ----
    for (int idx = tid; idx < TIH * TIW; idx += 256) {
        int rr = idx / TIW;
        int cc = idx - rr * TIW;
        int gr = tileY + rr - HALO;
        int gc = tileX + cc - HALO;
        unsigned char v = 0;
        if ((unsigned)gr < 1024u && (unsigned)gc < 1024u)
            v = (unsigned char)tgt[gr * 1024 + gc];
        tb[rr][cc] = v;
    }
    __syncthreads();

    // ---- Phase B: vertical sliding column sums over 11 rows ----
    if (tid < TIW) {
        int acc = 0;
        #pragma unroll
        for (int rr = 0; rr < 11; ++rr) acc += tb[rr][tid];
        vs[0][tid] = (unsigned short)acc;
        for (int r = 1; r < TH; ++r) {
            acc += (int)tb[r + 10][tid] - (int)tb[r - 1][tid];
            vs[r][tid] = (unsigned short)acc;
        }
    }
    __syncthreads();

    // ---- Phase C: per-pixel loss terms ----
    const float* s0b = score0 + (size_t)b * (2 * 1024 * 1024);
    const float* s1b = score1 + (size_t)b * (2 * 1024 * 1024);
    const int tx = tid & 31;   // 32 threads * 4 cols = 128
    const int ty = tid >> 5;   // 8 rows per pass, 4 passes = 32

    float cnt = 0.f, a1 = 0.f, a2 = 0.f, b1 = 0.f, b2 = 0.f;

    #pragma unroll
    for (int p = 0; p < 4; ++p) {
        const int r  = ty + p * 8;        // local output row 0..31
        const int gr = tileY + r;
        const int c0 = tx * 4;            // local output col
        const int gc = tileX + c0;

        // horizontal sliding window of 11 over column sums
        int S[4];
        int s = 0;
        #pragma unroll
        for (int k = 0; k < 11; ++k) s += vs[r][c0 + k];
        S[0] = s;
        #pragma unroll
        for (int j = 1; j < 4; ++j) {
            s += (int)vs[r][c0 + 10 + j] - (int)vs[r][c0 + j - 1];
            S[j] = s;
        }

        const size_t base = (size_t)gr * 1024 + gc;
        float4 x0 = *(const float4*)(s0b + base);            // score0 class0
        float4 x1 = *(const float4*)(s0b + 1048576 + base);  // score0 class1
        float4 y0 = *(const float4*)(s1b + base);            // score1 class0
        float4 y1 = *(const float4*)(s1b + 1048576 + base);  // score1 class1
        float p0a[4] = {x0.x, x0.y, x0.z, x0.w};
        float p1a[4] = {x1.x, x1.y, x1.z, x1.w};
        float q0a[4] = {y0.x, y0.y, y0.z, y0.w};
        float q1a[4] = {y1.x, y1.y, y1.z, y1.w};

        #pragma unroll
        for (int j = 0; j < 4; ++j) {
            const int t = tb[r + 5][c0 + 5 + j];
            // edge = 121*t_c - boxsum; exact integer predicate
            const float e = (S[j] != 121 * t) ? 1.0f : 0.0f;
            cnt += e;

            {   // score0
                float p0 = p0a[j], p1 = p1a[j];
                float m   = fmaxf(p0, p1);
                float lse = m + __logf(1.0f + __expf(-fabsf(p0 - p1)));
                float lpt = (t ? p1 : p0) - lse;
                float slp = p0 + p1 - 2.0f * lse;
                a1 += lpt;
                a2 += e * (slp - 1.5f * lpt);
            }
            {   // score1
                float q0 = q0a[j], q1 = q1a[j];
                float m   = fmaxf(q0, q1);
                float lse = m + __logf(1.0f + __expf(-fabsf(q0 - q1)));
                float lpt = (t ? q1 : q0) - lse;
                float slp = q0 + q1 - 2.0f * lse;
                b1 += lpt;
                b2 += e * (slp - 1.5f * lpt);
            }
        }
    }

    // ---- Block reduction -> per-block partials (no atomics) ----
    float vals[5] = {cnt, a1, a2, b1, b2};
    const int lane = tid & 63, wv = tid >> 6;
    #pragma unroll
    for (int q = 0; q < 5; ++q) {
        float v = vals[q];
        #pragma unroll
        for (int off = 32; off > 0; off >>= 1) v += __shfl_down(v, off);
        if (lane == 0) red[wv][q] = v;
    }
    __syncthreads();
    if (tid == 0) {
        #pragma unroll
        for (int q = 0; q < 5; ++q) {
            float v = red[0][q] + red[1][q] + red[2][q] + red[3][q];
            ws[q * NB + bid] = v;
        }
    }
}

// Final reduction + scalar loss. One block.
__global__ __launch_bounds__(256)
void finalize_loss(const float* __restrict__ ws, float* __restrict__ out) {
    __shared__ double red[4][5];
    const int tid = threadIdx.x;
    double acc[5] = {0, 0, 0, 0, 0};
    for (int i = tid; i < NB; i += 256) {
        #pragma unroll
        for (int q = 0; q < 5; ++q) acc[q] += (double)ws[q * NB + i];
    }
    const int lane = tid & 63, wv = tid >> 6;
    #pragma unroll
    for (int q = 0; q < 5; ++q) {
        double v = acc[q];
        #pragma unroll
        for (int off = 32; off > 0; off >>= 1) v += __shfl_down(v, off);
        if (lane == 0) red[wv][q] = v;
    }
    __syncthreads();
    if (tid == 0) {
        double s[5];
        #pragma unroll
        for (int q = 0; q < 5; ++q)
            s[q] = red[0][q] + red[1][q] + red[2][q] + red[3][q];
        const double N = NPIX;
        double alpha = s[0] / N;
        if (alpha > 0.2) alpha = 0.2;
        double loss = (s[1] + alpha * s[2]) + 0.5 * (s[3] + alpha * s[4]);
        out[0] = (float)(-loss / N);
    }
}

extern "C" void kernel_launch(void* const* d_in, const int* in_sizes, int n_in,
                              void* d_out, int out_size, void* d_ws, size_t ws_size,
                              hipStream_t stream) {
    const float* score0 = (const float*)d_in[0];
    const float* score1 = (const float*)d_in[1];
    const int*   target = (const int*)d_in[2];
    float* out = (float*)d_out;
    float* ws  = (float*)d_ws;   // needs 5*4096*4 = 80 KB

    dim3 grid(NBX, NBY, NBZ);
    fused_edge_loss<<<grid, 256, 0, stream>>>(score0, score1, target, ws);
    finalize_loss<<<1, 256, 0, stream>>>(ws, out);
}